// Round 3
// baseline (278.350 us; speedup 1.0000x reference)
//
#include <hip/hip_runtime.h>
#include <math.h>

// Problem: B=32, T=512, F=64, O=64.
// delta[b,t,f] = (t==0) ? 0 : in[b,t,f]-in[b,t-1,f]
// x = (delta - bn_mean) * (bn_w * rsqrt(bn_var+1e-5)) + bn_b
// enc_o = x * enc_w[o] + enc_b[o]
// LIF scan over o: h = v + (enc_o - v)/2 ; s = (h>=1) ; v = s?0:h
// out[b,o,f,t] = s   (fp32, 0/1)
//
// R4: XCD-aware swizzle (kept) — each XCD owns a contiguous 32 MiB
//     output range.
// R5: nontemporal stores — REGRESSED (+6 µs). L2 write policy is not
//     the lever. Reverted.
// R6: o-split 2x occupancy — NEUTRAL. Wave count / stream count is not
//     the lever either.
// R7 (this round): FAT BLOCKS for 4x contiguous run length. All prior
// schedules wrote 4 KiB per block per o-step (2 f-columns) then jumped
// 128 KiB -> per-HBM-channel fragments too short for row reuse.
// 1024-thread blocks cover 8 f-columns -> 16 KiB contiguous per o-step,
// 4x fewer concurrent streams (512 blocks), same per-thread state, same
// bytes, bitwise-identical arithmetic. o-split kept: 2 blocks/CU x 16
// waves = 32 waves/CU.

#define B_DIM 32
#define T_DIM 512
#define F_DIM 64
#define O_DIM 64

typedef float v4f __attribute__((ext_vector_type(4)));

__global__ __launch_bounds__(1024) void delta_lif_kernel(
    const float* __restrict__ in,     // [B,T,F]
    const float* __restrict__ enc_w,  // [64] (O,1)
    const float* __restrict__ enc_b,  // [64]
    const float* __restrict__ bn_w,   // [1]
    const float* __restrict__ bn_b,   // [1]
    const float* __restrict__ bn_mean,// [1]
    const float* __restrict__ bn_var, // [1]
    float* __restrict__ out)          // [B,O,F,T]
{
#pragma clang fp contract(off)
    // BatchNorm scalars — replicate reference op order exactly.
    const float vpe  = bn_var[0] + 1e-5f;
    const float r    = (float)(1.0 / sqrt((double)vpe));
    const float inv  = bn_w[0] * r;
    const float mean = bn_mean[0];
    const float bnb  = bn_b[0];

    // XCD swizzle: 512 blocks = 8 XCDs x 64 consecutive vbids.
    // vbid -> (group = vbid>>1, half = vbid&1). Each XCD: 32 groups
    // = 4 consecutive b's = 32 MiB contiguous output range.
    const int bid   = blockIdx.x;                // 0..511
    const int vbid  = ((bid & 7) << 6) + (bid >> 3);
    const int group = vbid >> 1;                 // 0..255: (b, f-octet)
    const int half  = vbid & 1;                  // o-half: 0 -> 0..31, 1 -> 32..63

    // Block covers 8 consecutive f's of one b: f = (group&7)*8 + (lt>>7),
    // t0 = (lt&127)*4. Per o-step the block stores 8 f x 512 t x 4 B
    // = 16 KiB CONTIGUOUS.
    const int lt = threadIdx.x;                  // 0..1023
    const int b  = group >> 3;
    const int f  = ((group & 7) << 3) + (lt >> 7);
    const int t0 = (lt & 127) << 2;

    // input: in[b, t, f] = in[b*T*F + t*F + f]
    const float* pin = in + b * (T_DIM * F_DIM) + f;
    const float c0 = pin[(t0 + 0) * F_DIM];
    const float c1 = pin[(t0 + 1) * F_DIM];
    const float c2 = pin[(t0 + 2) * F_DIM];
    const float c3 = pin[(t0 + 3) * F_DIM];
    const float p  = (t0 == 0) ? c0 : pin[(t0 - 1) * F_DIM];

    const float x0 = ((c0 - p)  - mean) * inv + bnb;
    const float x1 = ((c1 - c0) - mean) * inv + bnb;
    const float x2 = ((c2 - c1) - mean) * inv + bnb;
    const float x3 = ((c3 - c2) - mean) * inv + bnb;

    float v0 = 0.0f, v1 = 0.0f, v2 = 0.0f, v3 = 0.0f;

    // out[b,o,f,t] = out[(b<<21) + (o<<15) + (f<<9) + t]
    float* pout = out + (b << 21) + (f << 9) + t0;

    const int o_begin = half << 5;   // 0 or 32

    // Silent warm-up: advance scan state to o_begin (no stores).
    // Same fp ops in same order -> bitwise-identical v.
#pragma unroll 8
    for (int o = 0; o < o_begin; ++o) {
        const float w  = enc_w[o];
        const float bb = enc_b[o];
        const float h0 = v0 + ((x0 * w + bb) - v0) * 0.5f;
        const float h1 = v1 + ((x1 * w + bb) - v1) * 0.5f;
        const float h2 = v2 + ((x2 * w + bb) - v2) * 0.5f;
        const float h3 = v3 + ((x3 * w + bb) - v3) * 0.5f;
        v0 = (h0 >= 1.0f) ? 0.0f : h0;
        v1 = (h1 >= 1.0f) ? 0.0f : h1;
        v2 = (h2 >= 1.0f) ? 0.0f : h2;
        v3 = (h3 >= 1.0f) ? 0.0f : h3;
    }

#pragma unroll 8
    for (int oi = 0; oi < 32; ++oi) {
        const int o = o_begin + oi;
        // wave-uniform -> scalar loads, no LDS round-trip
        const float w  = enc_w[o];
        const float bb = enc_b[o];

        const float e0 = x0 * w + bb;
        const float e1 = x1 * w + bb;
        const float e2 = x2 * w + bb;
        const float e3 = x3 * w + bb;

        // h = v + (e - v)/2 ; /2 exact -> *0.5f identical
        const float h0 = v0 + (e0 - v0) * 0.5f;
        const float h1 = v1 + (e1 - v1) * 0.5f;
        const float h2 = v2 + (e2 - v2) * 0.5f;
        const float h3 = v3 + (e3 - v3) * 0.5f;

        const bool g0 = (h0 >= 1.0f);
        const bool g1 = (h1 >= 1.0f);
        const bool g2 = (h2 >= 1.0f);
        const bool g3 = (h3 >= 1.0f);

        v4f s;
        s.x = g0 ? 1.0f : 0.0f;
        s.y = g1 ? 1.0f : 0.0f;
        s.z = g2 ? 1.0f : 0.0f;
        s.w = g3 ? 1.0f : 0.0f;

        v0 = g0 ? 0.0f : h0;
        v1 = g1 ? 0.0f : h1;
        v2 = g2 ? 0.0f : h2;
        v3 = g3 ? 0.0f : h3;

        *(v4f*)(pout + (o << 15)) = s;
    }
}

extern "C" void kernel_launch(void* const* d_in, const int* in_sizes, int n_in,
                              void* d_out, int out_size, void* d_ws, size_t ws_size,
                              hipStream_t stream) {
    const float* in      = (const float*)d_in[0];
    const float* enc_w   = (const float*)d_in[1];
    const float* enc_b   = (const float*)d_in[2];
    const float* bn_w    = (const float*)d_in[3];
    const float* bn_b    = (const float*)d_in[4];
    const float* bn_mean = (const float*)d_in[5];
    const float* bn_var  = (const float*)d_in[6];
    float* out = (float*)d_out;

    // 512 blocks (256 (b,f-octet) groups x 2 o-halves, XCD-swizzled)
    // x 1024 threads
    delta_lif_kernel<<<dim3(512), dim3(1024), 0, stream>>>(
        in, enc_w, enc_b, bn_w, bn_b, bn_mean, bn_var, out);
}